// Round 4
// baseline (198.315 us; speedup 1.0000x reference)
//
#include <hip/hip_runtime.h>

// Problem constants
#define BS   64
#define NA   900
#define NT   600
#define NSEL 300          // NA - NT
#define ED   256
#define AD   11
#define NC   10
#define HALF (NA / 2)     // 450 rows ranked per scan-block
#define QTR  (NA / 4)     // 225 = active scan threads per block (2 rows each)
#define CACHED_FLAG 0x40000000

// d_out layout (float offsets), outputs concatenated in return order:
// merged (BS,NA,ED+AD), new_conf (BS,NT), cf (BS,NT,ED), ca (BS,NT,AD)
#define OFF_MERGED  0
#define OFF_NEWCONF (BS * NA * (ED + AD))          // 15,379,200
#define OFF_CF      (OFF_NEWCONF + BS * NT)        // 15,417,600
#define OFF_CA      (OFF_CF + BS * NT * ED)        // 25,248,000

// Native clang vector types (__builtin_nontemporal_* rejects HIP_vector_type).
typedef float f32x4 __attribute__((ext_vector_type(4)));
typedef unsigned long long u64;
typedef u64 u64x2 __attribute__((ext_vector_type(2)));

// Monotone map: f32 -> u32 such that u(a) < u(b) iff a < b
__device__ __forceinline__ unsigned int fkey(float x) {
    unsigned int u = __float_as_uint(x);
    return (u & 0x80000000u) ? ~u : (u | 0x80000000u);
}

__device__ __forceinline__ float conf_max_row(const float* __restrict__ confidence,
                                              int b, int i) {
    const float* cp = confidence + ((size_t)b * NA + i) * NC;
    float m = cp[0];
    #pragma unroll
    for (int k = 1; k < NC; k++) m = fmaxf(m, cp[k]);
    return m;
}

// Counting-rank top-k: rank(i) = #{j : w_j > w_i} with w = (fkey << 32) | (NA-1-i).
// u64 compare gives the exact jax top_k order (value desc, ties -> lower index).
// Ranks form a permutation, so scatter-by-rank writes each slot exactly once.
//
// LDS-issue economics (R3 post-mortem): ds_read issue cost is per-wave, so the
// scan cost = waves_per_CU x reads x 12cyc. Fix: each thread ranks TWO rows per
// ds_read_b128 (2 keys), and only 2 scan-blocks per (batch, sort) run per CU.
// grid = 4*BS blocks of 256 threads, bid = p*BS + b with p = (mode<<1)|part:
//   mode 0: src_map ranks over conf_max   (skipped entirely when !mask[b])
//   mode 1: new_conf/pos2 ranks over conf_c
// All 4 blocks of batch b share bid%64 = b -> same XCD -> the redundant
// 36 KB confidence re-read stays in that XCD's L2.
__global__ __launch_bounds__(256) void topk_kernel(
    const float* __restrict__ confidence,   // (BS, NA, NC)
    const float* __restrict__ prev_conf,    // (BS, NT)
    const int*   __restrict__ mask,         // (BS)
    float*       __restrict__ new_conf_out, // (BS, NT)
    int*         __restrict__ src_map,      // ws (BS, NA): source row per feat row
    int*         __restrict__ pos2)         // ws (BS, NA): feat row -> cf rank, or -1
{
    __shared__ __align__(16) u64 w_s[NA];   // rank keys
    __shared__ float cc_s[NA];              // conf_c values (mode 1)

    const int bid  = blockIdx.x;
    const int b    = bid & (BS - 1);        // batch
    const int p    = bid >> 6;              // 0..3
    const int mode = p >> 1;
    const int part = p & 1;
    const int t    = threadIdx.x;

    if (mode == 0) {
        const int mk = mask[b];             // block-uniform
        if (!mk) {
            // identity map for this 450-row slice; no ranking needed
            const int base = part * HALF;
            for (int i = t; i < HALF; i += 256)
                src_map[(size_t)b * NA + base + i] = base + i;
            return;
        }
        // cached-row init: rows [0,NT) split 300 per part-block
        {
            const int base = part * (NT / 2);
            for (int i = t; i < NT / 2; i += 256)
                src_map[(size_t)b * NA + base + i] = (base + i) | CACHED_FLAG;
        }
        // keys for all 900 rows (redundant across part-blocks, L2-local)
        for (int i = t; i < NA; i += 256) {
            float m = conf_max_row(confidence, b, i);
            w_s[i] = ((u64)fkey(m) << 32) | (unsigned int)(NA - 1 - i);
        }
        __syncthreads();
        if (t < QTR) {
            const int i0 = part * HALF + t;        // part0: 0..224, part1: 450..674
            const int i1 = i0 + QTR;               // part0: 225..449, part1: 675..899
            const u64 w0 = w_s[i0];
            const u64 w1 = w_s[i1];
            const u64x2* w2 = (const u64x2*)w_s;   // broadcast reads, conflict-free
            unsigned int c0 = 0, c1 = 0;
            #pragma unroll 5
            for (int j = 0; j < NA / 2; ++j) {
                const u64x2 q = w2[j];
                c0 += (unsigned int)(q.x > w0) + (unsigned int)(q.y > w0);
                c1 += (unsigned int)(q.x > w1) + (unsigned int)(q.y > w1);
            }
            if (c0 < NSEL) src_map[(size_t)b * NA + NT + c0] = i0;  // desc order
            if (c1 < NSEL) src_map[(size_t)b * NA + NT + c1] = i1;
        }
    } else {
        // conf_c = max(prev*0.6, sigmoid(cmax)) on first NT rows; sigmoid elsewhere
        for (int i = t; i < NA; i += 256) {
            float m = conf_max_row(confidence, b, i);
            double d = 1.0 / (1.0 + exp(-(double)m));   // sigmoid, rounded once
            float c = (float)d;
            if (i < NT) c = fmaxf(prev_conf[(size_t)b * NT + i] * 0.6f, c);
            cc_s[i] = c;
            w_s[i] = ((u64)fkey(c) << 32) | (unsigned int)(NA - 1 - i);
        }
        __syncthreads();
        if (t < QTR) {
            const int i0 = part * HALF + t;
            const int i1 = i0 + QTR;
            const u64 w0 = w_s[i0];
            const u64 w1 = w_s[i1];
            const u64x2* w2 = (const u64x2*)w_s;
            unsigned int c0 = 0, c1 = 0;
            #pragma unroll 5
            for (int j = 0; j < NA / 2; ++j) {
                const u64x2 q = w2[j];
                c0 += (unsigned int)(q.x > w0) + (unsigned int)(q.y > w0);
                c1 += (unsigned int)(q.x > w1) + (unsigned int)(q.y > w1);
            }
            if (c0 < NT) {
                new_conf_out[(size_t)b * NT + c0] = cc_s[i0];
                pos2[(size_t)b * NA + i0] = (int)c0;
            } else {
                pos2[(size_t)b * NA + i0] = -1;
            }
            if (c1 < NT) {
                new_conf_out[(size_t)b * NT + c1] = cc_s[i1];
                pos2[(size_t)b * NA + i1] = (int)c1;
            } else {
                pos2[(size_t)b * NA + i1] = -1;
            }
        }
    }
}

// One wave (64 lanes) per feat row. Writes merged row; if the row is in the
// second top-k (pos2 >= 0), also writes the cf/ca row from the same registers.
// All traffic is single-use -> non-temporal hints keep L2 clean.
__global__ __launch_bounds__(256) void gather_kernel(
    const float* __restrict__ inst_f,   // (BS, NA, ED)
    const float* __restrict__ anchor,   // (BS, NA, AD)
    const float* __restrict__ cached_f, // (BS, NT, ED)
    const float* __restrict__ cached_a, // (BS, NT, AD)
    const int*   __restrict__ src_map,  // (BS, NA)
    const int*   __restrict__ pos2,     // (BS, NA)
    float*       __restrict__ out)
{
    const int wave = threadIdx.x >> 6;
    const int lane = threadIdx.x & 63;
    const int gr   = blockIdx.x * 4 + wave;
    if (gr >= BS * NA) return;

    const int b = gr / NA;
    const int t = gr - b * NA;

    // Independent loads (chain depth 2: map -> data).
    const int s = src_map[(size_t)b * NA + t];
    const int p = pos2[(size_t)b * NA + t];

    const float* fsrc;
    const float* asrc;
    if (s & CACHED_FLAG) {
        const int r = s & 0xFFFF;
        fsrc = cached_f + ((size_t)b * NT + r) * ED;
        asrc = cached_a + ((size_t)b * NT + r) * AD;
    } else {
        fsrc = inst_f + ((size_t)b * NA + s) * ED;
        asrc = anchor + ((size_t)b * NA + s) * AD;
    }

    // Source feature row: 16B-aligned -> one float4 load per lane.
    const f32x4 v = __builtin_nontemporal_load((const f32x4*)fsrc + lane);
    float av = 0.0f;
    if (lane < AD) av = asrc[lane];

    // merged row: 267 floats, 1068 B pitch (not 16B-aligned) -> scalar stores;
    // a wave's 4 stores still cover one contiguous 1024 B span.
    float* orow = out + OFF_MERGED + ((size_t)b * NA + t) * (ED + AD);
    __builtin_nontemporal_store(v.x, orow + 4 * lane + 0);
    __builtin_nontemporal_store(v.y, orow + 4 * lane + 1);
    __builtin_nontemporal_store(v.z, orow + 4 * lane + 2);
    __builtin_nontemporal_store(v.w, orow + 4 * lane + 3);
    if (lane < AD) __builtin_nontemporal_store(av, orow + ED + lane);

    // cf/ca row (aligned) from the same registers — no second read of the source.
    if (p >= 0) {
        f32x4* crow = (f32x4*)(out + OFF_CF + ((size_t)b * NT + p) * ED);
        __builtin_nontemporal_store(v, crow + lane);
        if (lane < AD)
            __builtin_nontemporal_store(av, out + OFF_CA + ((size_t)b * NT + p) * AD + lane);
    }
}

extern "C" void kernel_launch(void* const* d_in, const int* in_sizes, int n_in,
                              void* d_out, int out_size, void* d_ws, size_t ws_size,
                              hipStream_t stream) {
    const float* inst_f = (const float*)d_in[0];
    const float* anchor = (const float*)d_in[1];
    const float* conf   = (const float*)d_in[2];
    const float* cach_f = (const float*)d_in[3];
    const float* cach_a = (const float*)d_in[4];
    const float* prevc  = (const float*)d_in[5];
    const int*   mask   = (const int*)d_in[6];
    float* out = (float*)d_out;

    int* src_map = (int*)d_ws;              // BS*NA ints
    int* pos2    = src_map + BS * NA;       // BS*NA ints

    topk_kernel<<<4 * BS, 256, 0, stream>>>(conf, prevc, mask,
                                            out + OFF_NEWCONF, src_map, pos2);

    const int nrows = BS * NA;
    gather_kernel<<<(nrows + 3) / 4, 256, 0, stream>>>(
        inst_f, anchor, cach_f, cach_a, src_map, pos2, out);
}

// Round 5
// 190.218 us; speedup vs baseline: 1.0426x; 1.0426x over previous
//
#include <hip/hip_runtime.h>

// Problem constants
#define BS   64
#define NA   900
#define NT   600
#define NSEL 300          // NA - NT
#define ED   256
#define AD   11
#define NC   10
#define SORTN 1024
#define CACHED_FLAG 0x40000000

// d_out layout (float offsets), outputs concatenated in return order:
// merged (BS,NA,ED+AD), new_conf (BS,NT), cf (BS,NT,ED), ca (BS,NT,AD)
#define OFF_MERGED  0
#define OFF_NEWCONF (BS * NA * (ED + AD))          // 15,379,200
#define OFF_CF      (OFF_NEWCONF + BS * NT)        // 15,417,600
#define OFF_CA      (OFF_CF + BS * NT * ED)        // 25,248,000

// Native clang vector type: __builtin_nontemporal_* requires a true vector,
// not HIP_vector_type<float,4> (a struct).
typedef float f32x4 __attribute__((ext_vector_type(4)));

// Monotone map: f32 -> u32 such that u(a) < u(b) iff a < b
__device__ __forceinline__ unsigned int fkey(float x) {
    unsigned int u = __float_as_uint(x);
    return (u & 0x80000000u) ? ~u : (u | 0x80000000u);
}

__device__ __forceinline__ unsigned long long shfl_xor64(unsigned long long v, int m) {
    return (unsigned long long)__shfl_xor((long long)v, m, 64);
}

// Register-resident bitonic sort of 1024 keys across 1024 threads.
// Thread i owns key i. j<64 phases: __shfl_xor (no barrier). j>=64: LDS exchange.
// Keys unique (index in low bits) so min/max compare-exchange is exact.
__device__ __forceinline__ void sort1024(unsigned long long& key, int i,
                                         unsigned long long* lds) {
    for (int k = 2; k <= SORTN; k <<= 1) {
        for (int j = k >> 1; j > 0; j >>= 1) {
            unsigned long long partner;
            if (j >= 64) {
                __syncthreads();
                lds[i] = key;
                __syncthreads();
                partner = lds[i ^ j];
            } else {
                partner = shfl_xor64(key, j);
            }
            const bool up      = ((i & k) == 0);
            const bool lower   = ((i & j) == 0);
            const bool keepmin = (lower == up);
            const bool pgt     = (key > partner);
            key = (keepmin == pgt) ? partner : key;
        }
    }
}

__device__ __forceinline__ float conf_max_row(const float* __restrict__ confidence,
                                              int b, int i) {
    const float* cp = confidence + ((size_t)b * NA + i) * NC;
    float m = cp[0];
    #pragma unroll
    for (int k = 1; k < NC; k++) m = fmaxf(m, cp[k]);
    return m;
}

// grid = 2*BS. The two sorts are data-independent (sort2's conf_c depends only
// on cmax + prev_conf, not on sort1's output), so run them in parallel blocks:
//   even blocks: sort1 over conf_max  -> src_map          (skipped if !mask)
//   odd  blocks: sort2 over conf_c    -> new_conf, pos2
// Re-computing cmax in both blocks costs a trivial 36 KB/batch confidence read.
__global__ __launch_bounds__(1024) void topk_kernel(
    const float* __restrict__ confidence,   // (BS, NA, NC)
    const float* __restrict__ prev_conf,    // (BS, NT)
    const int*   __restrict__ mask,         // (BS)
    float*       __restrict__ new_conf_out, // (BS, NT)
    int*         __restrict__ src_map,      // ws (BS, NA): source row per feat row
    int*         __restrict__ pos2)         // ws (BS, NA): feat row -> cf rank, or -1
{
    __shared__ unsigned long long keys[SORTN];   // bitonic exchange buffer
    __shared__ float cc_s[NA];                   // conf_c values (sort2 only)

    const int b = blockIdx.x >> 1;
    const int i = threadIdx.x;

    if ((blockIdx.x & 1) == 0) {
        // ---------- sort1: top-300 rows of conf_max -> src_map ----------
        const int mk = mask[b];                  // block-uniform
        if (!mk) {
            // identity map; no sort needed
            if (i < NA) src_map[(size_t)b * NA + i] = i;
            return;
        }
        if (i < NT) src_map[(size_t)b * NA + i] = i | CACHED_FLAG;

        float cmax = (i < NA) ? conf_max_row(confidence, b, i) : 0.0f;
        unsigned long long key = (i < NA)
            ? ((((unsigned long long)(~fkey(cmax))) << 32) | (unsigned int)i)
            : 0xFFFFFFFFFFFFFFFFull;
        sort1024(key, i, keys);
        // Thread i now holds descending rank i directly -> no LDS rank publish.
        if (i < NSEL)
            src_map[(size_t)b * NA + NT + i] = (int)(key & 0xFFFFFFFFull);
    } else {
        // ---------- sort2: conf_c ranking -> new_conf + inverse map pos2 ----------
        float c = 0.0f;
        if (i < NA) {
            float cmax = conf_max_row(confidence, b, i);
            double d = 1.0 / (1.0 + exp(-(double)cmax));   // sigmoid, rounded once
            c = (float)d;
            if (i < NT) c = fmaxf(prev_conf[(size_t)b * NT + i] * 0.6f, c);
            cc_s[i] = c;
        }
        unsigned long long key = (i < NA)
            ? ((((unsigned long long)(~fkey(c))) << 32) | (unsigned int)i)
            : 0xFFFFFFFFFFFFFFFFull;
        sort1024(key, i, keys);   // contains barriers -> cc_s visible afterwards
        // Ranks [0,NA) hold each real row exactly once; padding keys sort
        // strictly last (conf_c in (0,1); padding key is the unique max).
        if (i < NT) {
            int r = (int)(key & 0xFFFFFFFFull);
            new_conf_out[(size_t)b * NT + i] = cc_s[r];
            pos2[(size_t)b * NA + r] = i;
        } else if (i < NA) {
            int r = (int)(key & 0xFFFFFFFFull);
            pos2[(size_t)b * NA + r] = -1;
        }
    }
}

// One wave (64 lanes) per feat row. Writes merged row; if the row is in the
// second top-k (pos2 >= 0), also writes the cf/ca row from the same registers.
// All traffic is single-use -> non-temporal hints keep L2 clean.
__global__ __launch_bounds__(256) void gather_kernel(
    const float* __restrict__ inst_f,   // (BS, NA, ED)
    const float* __restrict__ anchor,   // (BS, NA, AD)
    const float* __restrict__ cached_f, // (BS, NT, ED)
    const float* __restrict__ cached_a, // (BS, NT, AD)
    const int*   __restrict__ src_map,  // (BS, NA)
    const int*   __restrict__ pos2,     // (BS, NA)
    float*       __restrict__ out)
{
    const int wave = threadIdx.x >> 6;
    const int lane = threadIdx.x & 63;
    const int gr   = blockIdx.x * 4 + wave;
    if (gr >= BS * NA) return;

    const int b = gr / NA;
    const int t = gr - b * NA;

    // Independent loads (chain depth 2: map -> data).
    const int s = src_map[(size_t)b * NA + t];
    const int p = pos2[(size_t)b * NA + t];

    const float* fsrc;
    const float* asrc;
    if (s & CACHED_FLAG) {
        const int r = s & 0xFFFF;
        fsrc = cached_f + ((size_t)b * NT + r) * ED;
        asrc = cached_a + ((size_t)b * NT + r) * AD;
    } else {
        fsrc = inst_f + ((size_t)b * NA + s) * ED;
        asrc = anchor + ((size_t)b * NA + s) * AD;
    }

    // Source feature row: 16B-aligned -> one float4 load per lane.
    const f32x4 v = __builtin_nontemporal_load((const f32x4*)fsrc + lane);
    float av = 0.0f;
    if (lane < AD) av = asrc[lane];

    // merged row: 267 floats, 1068 B pitch (not 16B-aligned) -> scalar stores;
    // a wave's 4 stores still cover one contiguous 1024 B span.
    float* orow = out + OFF_MERGED + ((size_t)b * NA + t) * (ED + AD);
    __builtin_nontemporal_store(v.x, orow + 4 * lane + 0);
    __builtin_nontemporal_store(v.y, orow + 4 * lane + 1);
    __builtin_nontemporal_store(v.z, orow + 4 * lane + 2);
    __builtin_nontemporal_store(v.w, orow + 4 * lane + 3);
    if (lane < AD) __builtin_nontemporal_store(av, orow + ED + lane);

    // cf/ca row (aligned) from the same registers — no second read of the source.
    if (p >= 0) {
        f32x4* crow = (f32x4*)(out + OFF_CF + ((size_t)b * NT + p) * ED);
        __builtin_nontemporal_store(v, crow + lane);
        if (lane < AD)
            __builtin_nontemporal_store(av, out + OFF_CA + ((size_t)b * NT + p) * AD + lane);
    }
}

extern "C" void kernel_launch(void* const* d_in, const int* in_sizes, int n_in,
                              void* d_out, int out_size, void* d_ws, size_t ws_size,
                              hipStream_t stream) {
    const float* inst_f = (const float*)d_in[0];
    const float* anchor = (const float*)d_in[1];
    const float* conf   = (const float*)d_in[2];
    const float* cach_f = (const float*)d_in[3];
    const float* cach_a = (const float*)d_in[4];
    const float* prevc  = (const float*)d_in[5];
    const int*   mask   = (const int*)d_in[6];
    float* out = (float*)d_out;

    int* src_map = (int*)d_ws;              // BS*NA ints
    int* pos2    = src_map + BS * NA;       // BS*NA ints

    topk_kernel<<<2 * BS, 1024, 0, stream>>>(conf, prevc, mask,
                                             out + OFF_NEWCONF, src_map, pos2);

    const int nrows = BS * NA;
    gather_kernel<<<(nrows + 3) / 4, 256, 0, stream>>>(
        inst_f, anchor, cach_f, cach_a, src_map, pos2, out);
}